// Round 1
// baseline (237.680 us; speedup 1.0000x reference)
//
#include <hip/hip_runtime.h>

#define L_LAYERS 8
#define N_NODES 100000
#define H_DIM 128
#define K_TOT 1024   // L_LAYERS * H_DIM
#define BM 128
#define LDK 72       // padded LDS k-stride (bf16 elems): 64 + 8 -> breaks 128B-stride bank conflict

typedef __attribute__((ext_vector_type(4))) float f32x4;
typedef __attribute__((ext_vector_type(8))) short bf16x8;

__device__ __forceinline__ unsigned short f2bf(float f) {
    unsigned u = __float_as_uint(f);
    unsigned r = ((u >> 16) & 1u) + 0x7fffu;   // round-to-nearest-even
    return (unsigned short)((u + r) >> 16);
}
__device__ __forceinline__ float bf2f(unsigned short s) {
    return __uint_as_float(((unsigned)s) << 16);
}

// One fused kernel: per block of BM=128 nodes:
//  phase 1: K-loop (16 steps of BK=64): stage xs->A(bf16), w_ref->B(bf16) in LDS,
//           MFMA jk accumulation, VALU s_x partial from the staged A tile.
//  phase 2: PReLU(+b_ref), s_jk = jk . wa_ref (shfl butterfly), scores, softmax -> W in LDS.
//  phase 3: out[n,h] = sum_l W[l,n]*xs[l,n,h], coalesced re-read of xs.
__global__ __launch_bounds__(256, 2)
void gamlp_fused(const float* __restrict__ xs,
                 const float* __restrict__ w_ref,
                 const float* __restrict__ b_ref,
                 const float* __restrict__ w_att,
                 const float* __restrict__ b_att_p,
                 const float* __restrict__ alpha_p,
                 float* __restrict__ out)
{
    __shared__ unsigned short A_lds[BM][LDK];
    __shared__ unsigned short B_lds[H_DIM][LDK];
    __shared__ float sx_lds[2][L_LAYERS][BM];   // [k-half][l][node]
    __shared__ float sjk_lds[BM][2];            // [node][wn]
    __shared__ float w_lds[L_LAYERS][BM];       // softmax weights
    __shared__ float wax_lds[H_DIM];            // wa_x staged

    const int tid  = threadIdx.x;
    const int lane = tid & 63;
    const int wave = tid >> 6;
    const int wm   = wave >> 1;    // row-group 0..1 (64 rows each)
    const int wn   = wave & 1;     // col-group 0..1 (64 cols each)
    const int n0   = blockIdx.x * BM;
    const int cnt  = min(BM, N_NODES - n0);
    const bool full = (cnt == BM);

    if (tid < H_DIM) wax_lds[tid] = w_att[H_DIM + tid];
    const float alpha = *alpha_p;
    const float batt  = *b_att_p;

    f32x4 acc[4][4];
    #pragma unroll
    for (int m = 0; m < 4; m++)
        #pragma unroll
        for (int n = 0; n < 4; n++) acc[m][n] = (f32x4){0.f, 0.f, 0.f, 0.f};

    const int sx_node = tid & 127;
    const int sx_half = tid >> 7;

    for (int l = 0; l < L_LAYERS; ++l) {
        float sx_run = 0.f;
        for (int s2 = 0; s2 < 2; ++s2) {
            const int k0 = l * 128 + s2 * 64;   // global k base of this step
            const int h0 = s2 * 64;             // h offset within layer l
            __syncthreads();   // previous step's LDS reads done
            // ---- stage A: 128 nodes x 64 k, f32 global -> bf16 LDS ----
            #pragma unroll
            for (int i = 0; i < 8; i++) {
                int j = tid + i * 256;          // float4 index, 2048 total
                int node = j >> 4;
                int p = (j & 15) << 2;          // 0..60
                float4 v = {0.f, 0.f, 0.f, 0.f};
                if (full || node < cnt)
                    v = *reinterpret_cast<const float4*>(
                        xs + (size_t)l * N_NODES * H_DIM + (size_t)(n0 + node) * H_DIM + h0 + p);
                ushort4 pk;
                pk.x = f2bf(v.x); pk.y = f2bf(v.y); pk.z = f2bf(v.z); pk.w = f2bf(v.w);
                *reinterpret_cast<ushort4*>(&A_lds[node][p]) = pk;
            }
            // ---- stage B: 128 cols x 64 k (w_ref row-major, k contiguous) ----
            #pragma unroll
            for (int i = 0; i < 8; i++) {
                int j = tid + i * 256;
                int col = j >> 4;
                int p = (j & 15) << 2;
                float4 v = *reinterpret_cast<const float4*>(
                    w_ref + (size_t)col * K_TOT + k0 + p);
                ushort4 pk;
                pk.x = f2bf(v.x); pk.y = f2bf(v.y); pk.z = f2bf(v.z); pk.w = f2bf(v.w);
                *reinterpret_cast<ushort4*>(&B_lds[col][p]) = pk;
            }
            __syncthreads();
            // ---- MFMA: C[node, col] += A . B  (two k-chunks of 32) ----
            #pragma unroll
            for (int c = 0; c < 2; c++) {
                bf16x8 af[4], bfv[4];
                #pragma unroll
                for (int m = 0; m < 4; m++)
                    af[m] = *reinterpret_cast<const bf16x8*>(
                        &A_lds[wm * 64 + m * 16 + (lane & 15)][c * 32 + (lane >> 4) * 8]);
                #pragma unroll
                for (int n = 0; n < 4; n++)
                    bfv[n] = *reinterpret_cast<const bf16x8*>(
                        &B_lds[wn * 64 + n * 16 + (lane & 15)][c * 32 + (lane >> 4) * 8]);
                #pragma unroll
                for (int m = 0; m < 4; m++)
                    #pragma unroll
                    for (int n = 0; n < 4; n++)
                        acc[m][n] = __builtin_amdgcn_mfma_f32_16x16x32_bf16(
                            af[m], bfv[n], acc[m][n], 0, 0, 0);
            }
            // ---- s_x partial: dot(A_lds[node][half*32..], wa_x) ----
            {
                float s = 0.f;
                #pragma unroll
                for (int q4 = 0; q4 < 4; q4++) {
                    bf16x8 av = *reinterpret_cast<const bf16x8*>(&A_lds[sx_node][sx_half * 32 + q4 * 8]);
                    f32x4 wv0 = *reinterpret_cast<const f32x4*>(&wax_lds[h0 + sx_half * 32 + q4 * 8]);
                    f32x4 wv1 = *reinterpret_cast<const f32x4*>(&wax_lds[h0 + sx_half * 32 + q4 * 8 + 4]);
                    #pragma unroll
                    for (int e = 0; e < 4; e++) s += bf2f((unsigned short)av[e]) * wv0[e];
                    #pragma unroll
                    for (int e = 0; e < 4; e++) s += bf2f((unsigned short)av[e + 4]) * wv1[e];
                }
                sx_run += s;
            }
        }
        sx_lds[sx_half][l][sx_node] = sx_run;   // unique (half,l,node) per thread: no race
    }

    // ---- PReLU(+b_ref) and s_jk = sum_col jk*wa_ref ----
    // C layout (verified m89): col = lane&15, row = (lane>>4)*4 + reg
    float wr[4], br[4];
    #pragma unroll
    for (int n = 0; n < 4; n++) {
        int col = wn * 64 + n * 16 + (lane & 15);
        wr[n] = w_att[col];    // wa_ref
        br[n] = b_ref[col];
    }
    float sp[4][4];
    #pragma unroll
    for (int m = 0; m < 4; m++)
        #pragma unroll
        for (int r = 0; r < 4; r++) {
            float s = 0.f;
            #pragma unroll
            for (int n = 0; n < 4; n++) {
                float v = acc[m][n][r] + br[n];
                v = (v >= 0.f) ? v : alpha * v;    // PReLU
                s += v * wr[n];
            }
            // butterfly over the 16-lane col group -> sum over this wave's 64 cols
            s += __shfl_xor(s, 1);
            s += __shfl_xor(s, 2);
            s += __shfl_xor(s, 4);
            s += __shfl_xor(s, 8);
            sp[m][r] = s;
        }
    if ((lane & 15) == 0) {
        int g = lane >> 4;
        #pragma unroll
        for (int m = 0; m < 4; m++)
            #pragma unroll
            for (int r = 0; r < 4; r++)
                sjk_lds[wm * 64 + m * 16 + g * 4 + r][wn] = sp[m][r];
    }
    __syncthreads();

    // ---- scores + softmax over L (one thread per node) ----
    if (tid < BM) {
        int node = tid;
        float sjk = sjk_lds[node][0] + sjk_lds[node][1];
        float sc[L_LAYERS];
        float mx = -1e30f;
        #pragma unroll
        for (int l = 0; l < L_LAYERS; l++) {
            float s = sjk + sx_lds[0][l][node] + sx_lds[1][l][node] + batt;
            s = fmaxf(s, 0.f);   // relu
            sc[l] = s;
            mx = fmaxf(mx, s);
        }
        float den = 0.f;
        #pragma unroll
        for (int l = 0; l < L_LAYERS; l++) { sc[l] = __expf(sc[l] - mx); den += sc[l]; }
        float inv = 1.f / den;
        #pragma unroll
        for (int l = 0; l < L_LAYERS; l++) w_lds[l][node] = sc[l] * inv;
    }
    __syncthreads();

    // ---- epilogue: out[n,h] = sum_l W[l,n] * xs[l,n,h], coalesced ----
    #pragma unroll
    for (int i = 0; i < 16; i++) {
        int f = tid + i * 256;      // float4 index over 128 nodes x 32 f4
        int node = f >> 5;
        int q = (f & 31) << 2;
        if (full || node < cnt) {
            const float* base = xs + (size_t)(n0 + node) * H_DIM + q;
            f32x4 a = (f32x4){0.f, 0.f, 0.f, 0.f};
            #pragma unroll
            for (int l = 0; l < L_LAYERS; l++) {
                f32x4 v = *reinterpret_cast<const f32x4*>(base + (size_t)l * N_NODES * H_DIM);
                float w = w_lds[l][node];
                a += w * v;
            }
            *reinterpret_cast<f32x4*>(out + (size_t)(n0 + node) * H_DIM + q) = a;
        }
    }
}

extern "C" void kernel_launch(void* const* d_in, const int* in_sizes, int n_in,
                              void* d_out, int out_size, void* d_ws, size_t ws_size,
                              hipStream_t stream) {
    const float* xs     = (const float*)d_in[0];
    const float* w_ref  = (const float*)d_in[1];
    const float* b_ref  = (const float*)d_in[2];
    const float* w_att  = (const float*)d_in[3];
    const float* b_att  = (const float*)d_in[4];
    const float* alpha  = (const float*)d_in[5];
    float* out = (float*)d_out;
    const int grid = (N_NODES + BM - 1) / BM;   // 782
    gamlp_fused<<<grid, 256, 0, stream>>>(xs, w_ref, b_ref, w_att, b_att, alpha, out);
}

// Round 2
// 163.687 us; speedup vs baseline: 1.4520x; 1.4520x over previous
//
#include <hip/hip_runtime.h>

#define LL 8
#define NN 100000
#define HH 128
#define KT 1024
#define BM 64

typedef __attribute__((ext_vector_type(4))) float f32x4;
typedef __attribute__((ext_vector_type(8))) short bf16x8;
typedef __attribute__((ext_vector_type(8))) unsigned short u16x8;

__device__ __forceinline__ unsigned short f2bf(float f) {
    unsigned u = __float_as_uint(f);
    unsigned r = ((u >> 16) & 1u) + 0x7fffu;   // RNE
    return (unsigned short)((u + r) >> 16);
}

// Pre-pack w_ref (f32 [128 cols][1024 k]) -> bf16 in fragment order:
// wp[(k8*128 + col)*8 + e] = bf16(w_ref[col][k8*8+e]),  k8 = k/8.
// A wave's B-fragment load is then 16 consecutive 16B chunks (256B contiguous).
__global__ __launch_bounds__(256) void pack_w_kernel(const float* __restrict__ w_ref,
                                                     unsigned short* __restrict__ wp) {
    int gid = blockIdx.x * 256 + threadIdx.x;   // 0..16383
    int col = gid >> 7;          // 0..127
    int k8  = gid & 127;         // 0..127
    const float* s = w_ref + (size_t)col * KT + (size_t)k8 * 8;
    float4 v0 = *reinterpret_cast<const float4*>(s);
    float4 v1 = *reinterpret_cast<const float4*>(s + 4);
    u16x8 p;
    p[0] = f2bf(v0.x); p[1] = f2bf(v0.y); p[2] = f2bf(v0.z); p[3] = f2bf(v0.w);
    p[4] = f2bf(v1.x); p[5] = f2bf(v1.y); p[6] = f2bf(v1.z); p[7] = f2bf(v1.w);
    *reinterpret_cast<u16x8*>(wp + (size_t)(k8 * 128 + col) * 8) = p;
}

// Fused main kernel. Block = 64 nodes, 256 threads = 4 waves.
// Each wave: full 64 nodes x 32 output cols (cols = wave*32..+31).
//  K-loop (16 steps of 64k): stage A (xs f32 -> bf16, XOR-swizzled 8KB LDS),
//    B fragments direct global->reg from packed bf16 (L2-resident), MFMA.
//  sjk = sum_col prelu(jk)*wa_ref via shfl butterfly + tiny LDS.
//  Epilogue (fully fused, per node): re-read xs f32 (L2/L3-hot), s_x = xs.wa_x
//    (f32, shfl-reduced over 32 lanes), relu-scores, softmax over L in-lane,
//    weighted sum from the stashed registers, store.
__global__ __launch_bounds__(256, 4)
void gamlp_main(const float* __restrict__ xs,
                const unsigned short* __restrict__ wp,
                const float* __restrict__ b_ref,
                const float* __restrict__ w_att,
                const float* __restrict__ b_att_p,
                const float* __restrict__ alpha_p,
                float* __restrict__ out)
{
    __shared__ unsigned short A_lds[BM * 64];   // 8 KB, slot = ks ^ (row&7)
    __shared__ float sjk_lds[BM][4];

    const int tid  = threadIdx.x;
    const int lane = tid & 63;
    const int wave = tid >> 6;
    const int n0   = blockIdx.x * BM;

    const float alpha = *alpha_p;
    const float batt  = *b_att_p;

    // ---- staging map: thread j (two iters) covers tile row j>>3, 16B slot j&7 ----
    const int j0 = tid, j1 = tid + 256;
    const int row0 = j0 >> 3, ks0 = j0 & 7;
    const int row1 = j1 >> 3, ks1 = j1 & 7;
    const float* src0 = xs + (size_t)min(n0 + row0, NN - 1) * HH + ks0 * 8;
    const float* src1 = xs + (size_t)min(n0 + row1, NN - 1) * HH + ks1 * 8;
    unsigned short* dst0 = A_lds + row0 * 64 + ((ks0 ^ (row0 & 7)) * 8);
    unsigned short* dst1 = A_lds + row1 * 64 + ((ks1 ^ (row1 & 7)) * 8);

    // ---- MFMA fragment addressing ----
    const int colq = lane & 15;      // 16-dim index within fragment
    const int kq   = lane >> 4;      // k-chunk 0..3
    int aoff[4][2];
    #pragma unroll
    for (int m = 0; m < 4; m++)
        #pragma unroll
        for (int c = 0; c < 2; c++) {
            int rr = m * 16 + colq;
            aoff[m][c] = rr * 64 + (((c * 4 + kq) ^ (rr & 7)) * 8);
        }
    const unsigned short* pB0 = wp + (size_t)(wave * 32 + colq) * 8;
    const unsigned short* pB1 = wp + (size_t)(wave * 32 + 16 + colq) * 8;

    float wr0 = w_att[wave * 32 + colq],      wr1 = w_att[wave * 32 + 16 + colq];
    float br0 = b_ref[wave * 32 + colq],      br1 = b_ref[wave * 32 + 16 + colq];

    f32x4 acc[4][2];
    #pragma unroll
    for (int m = 0; m < 4; m++) { acc[m][0] = (f32x4){0,0,0,0}; acc[m][1] = (f32x4){0,0,0,0}; }

    for (int step = 0; step < 16; ++step) {
        const int l = step >> 1, s2 = step & 1;
        const size_t goff = (size_t)l * (NN * HH) + (size_t)s2 * 64;
        __syncthreads();   // previous step's LDS reads done
        {
            f32x4 a0 = *reinterpret_cast<const f32x4*>(src0 + goff);
            f32x4 a1 = *reinterpret_cast<const f32x4*>(src0 + goff + 4);
            f32x4 b0 = *reinterpret_cast<const f32x4*>(src1 + goff);
            f32x4 b1 = *reinterpret_cast<const f32x4*>(src1 + goff + 4);
            u16x8 p0, p1;
            #pragma unroll
            for (int e = 0; e < 4; e++) { p0[e] = f2bf(a0[e]); p0[e+4] = f2bf(a1[e]); }
            #pragma unroll
            for (int e = 0; e < 4; e++) { p1[e] = f2bf(b0[e]); p1[e+4] = f2bf(b1[e]); }
            *reinterpret_cast<u16x8*>(dst0) = p0;
            *reinterpret_cast<u16x8*>(dst1) = p1;
        }
        __syncthreads();
        const int k8s = step * 8;     // = l*16 + s2*8
        #pragma unroll
        for (int c = 0; c < 2; c++) {
            bf16x8 af[4];
            #pragma unroll
            for (int m = 0; m < 4; m++)
                af[m] = *reinterpret_cast<const bf16x8*>(A_lds + aoff[m][c]);
            const size_t boff = (size_t)(k8s + c * 4 + kq) * 1024;
            bf16x8 bf0 = *reinterpret_cast<const bf16x8*>(pB0 + boff);
            bf16x8 bf1 = *reinterpret_cast<const bf16x8*>(pB1 + boff);
            #pragma unroll
            for (int m = 0; m < 4; m++) {
                acc[m][0] = __builtin_amdgcn_mfma_f32_16x16x32_bf16(af[m], bf0, acc[m][0], 0, 0, 0);
                acc[m][1] = __builtin_amdgcn_mfma_f32_16x16x32_bf16(af[m], bf1, acc[m][1], 0, 0, 0);
            }
        }
    }

    // ---- sjk: prelu(jk + b_ref) . wa_ref, summed over this wave's 32 cols ----
    // C layout: col = colq, node_local = m*16 + kq*4 + r
    #pragma unroll
    for (int m = 0; m < 4; m++)
        #pragma unroll
        for (int r = 0; r < 4; r++) {
            float v0 = acc[m][0][r] + br0;  v0 = (v0 >= 0.f) ? v0 : alpha * v0;
            float v1 = acc[m][1][r] + br1;  v1 = (v1 >= 0.f) ? v1 : alpha * v1;
            float s = v0 * wr0 + v1 * wr1;
            s += __shfl_xor(s, 1);
            s += __shfl_xor(s, 2);
            s += __shfl_xor(s, 4);
            s += __shfl_xor(s, 8);
            if (colq == 0) sjk_lds[m * 16 + kq * 4 + r][wave] = s;
        }
    __syncthreads();

    // ---- fused epilogue: s_x (f32) + softmax + weighted sum ----
    #pragma unroll
    for (int i = 0; i < 8; i++) {
        int f = tid + i * 256;          // 0..2047
        int node = f >> 5;              // 0..63
        int q = (f & 31) << 2;          // 0..124
        int ng = n0 + node;
        int ngc = min(ng, NN - 1);
        const float* base = xs + (size_t)ngc * HH + q;
        f32x4 wv = *reinterpret_cast<const f32x4*>(w_att + HH + q);
        f32x4 v[LL];
        float sx[LL];
        #pragma unroll
        for (int l = 0; l < LL; l++) {
            v[l] = *reinterpret_cast<const f32x4*>(base + (size_t)l * (NN * HH));
            sx[l] = v[l][0] * wv[0] + v[l][1] * wv[1] + v[l][2] * wv[2] + v[l][3] * wv[3];
        }
        #pragma unroll
        for (int l = 0; l < LL; l++) {
            float s = sx[l];
            s += __shfl_xor(s, 1);
            s += __shfl_xor(s, 2);
            s += __shfl_xor(s, 4);
            s += __shfl_xor(s, 8);
            s += __shfl_xor(s, 16);
            sx[l] = s;                  // all 32 lanes of the node-group hold full dot
        }
        float sjk = sjk_lds[node][0] + sjk_lds[node][1] + sjk_lds[node][2] + sjk_lds[node][3];
        float sc[LL], mx = 0.f;
        #pragma unroll
        for (int l = 0; l < LL; l++) {
            float s = sjk + sx[l] + batt;
            s = fmaxf(s, 0.f);
            sc[l] = s;
            mx = fmaxf(mx, s);
        }
        float den = 0.f;
        #pragma unroll
        for (int l = 0; l < LL; l++) { sc[l] = __expf(sc[l] - mx); den += sc[l]; }
        float inv = 1.f / den;
        f32x4 o = (f32x4){0, 0, 0, 0};
        #pragma unroll
        for (int l = 0; l < LL; l++) o += (sc[l] * inv) * v[l];
        if (ng < NN)
            *reinterpret_cast<f32x4*>(out + (size_t)ng * HH + q) = o;
    }
}

extern "C" void kernel_launch(void* const* d_in, const int* in_sizes, int n_in,
                              void* d_out, int out_size, void* d_ws, size_t ws_size,
                              hipStream_t stream) {
    const float* xs     = (const float*)d_in[0];
    const float* w_ref  = (const float*)d_in[1];
    const float* b_ref  = (const float*)d_in[2];
    const float* w_att  = (const float*)d_in[3];
    const float* b_att  = (const float*)d_in[4];
    const float* alpha  = (const float*)d_in[5];
    float* out = (float*)d_out;
    unsigned short* wp = (unsigned short*)d_ws;     // 256 KB packed bf16 weights

    pack_w_kernel<<<64, 256, 0, stream>>>(w_ref, wp);
    const int grid = (NN + BM - 1) / BM;            // 1563
    gamlp_main<<<grid, 256, 0, stream>>>(xs, wp, b_ref, w_att, b_att, alpha, out);
}